// Round 15
// baseline (91.617 us; speedup 1.0000x reference)
//
#include <hip/hip_runtime.h>

// Problem constants
constexpr int B  = 512, L = 50, N = 16, H = 128;
constexpr int C1 = 96, C2 = 48, C3 = 16;

typedef __bf16   bf16x8 __attribute__((ext_vector_type(8)));
typedef float    f32x4  __attribute__((ext_vector_type(4)));
typedef unsigned u32x4  __attribute__((ext_vector_type(4)));

__device__ __forceinline__ bf16x8 cvt8(float4 a, float4 b) {
  bf16x8 r;
  r[0] = (__bf16)a.x; r[1] = (__bf16)a.y; r[2] = (__bf16)a.z; r[3] = (__bf16)a.w;
  r[4] = (__bf16)b.x; r[5] = (__bf16)b.y; r[6] = (__bf16)b.z; r[7] = (__bf16)b.w;
  return r;
}
__device__ __forceinline__ float bf16lo(unsigned u) { return __uint_as_float(u << 16); }
__device__ __forceinline__ float bf16hi(unsigned u) { return __uint_as_float(u & 0xffff0000u); }
// pack two f32 -> one u32 of 2 bf16 (RNE), single instruction
__device__ __forceinline__ unsigned pkbf(float lo, float hi) {
  unsigned r;
  asm("v_cvt_pk_bf16_f32 %0, %1, %2" : "=v"(r) : "v"(lo), "v"(hi));
  return r;
}

// MFMA 16x16x32 bf16 lane mapping (verified m89/m91):
//   A: row = lane&15, k = 32*step + 8*(lane>>4) + j   (B identical, col=lane&15)
//   D: col = lane&15, row = 4*(lane>>4) + reg
//
// r15: body identical to r12 (best, 63.2 us). Single change: launch bounds
// (256,2) -> (256,1). Cap model: arch-VGPR cap = 512/(waves_per_SIMD_per_block
// * min_waves); (256,1) is the first config that permits >128 arch regs.
// r12's 8.2 MB spill = ~30 regs of demand above the 128 allocation; if the
// allocator takes ~160, spills die at zero occupancy cost (LDS 74.7 KB
// already pins 2 blocks/CU = 8 waves/CU).
// r14 lesson (refuted edits, both reverted): DPP rowsum = no gain (shfl_xor
// at dist<=8 already DPP-speed); packed-bf16 aggregate -> MORE spills
// (inline-asm pkbf x32/iter constrains regalloc worse than 16 regs help).
__global__ __launch_bounds__(256, 1) void fused_kernel(
    const int*   __restrict__ user_ids,      // [B]
    const int*   __restrict__ history,       // [B][L]
    const float* __restrict__ neighbor_emb,  // [B][L][N][H]
    const float* __restrict__ user_table,    // [100000][H]
    const float* __restrict__ item_table,    // [100000][H]
    const float* __restrict__ Wa,  const float* __restrict__ ba,
    const float* __restrict__ W1,  const float* __restrict__ b1,
    const float* __restrict__ W2,  const float* __restrict__ b2,
    const float* __restrict__ W3,
    const float* __restrict__ Wmh,  const float* __restrict__ bmh,
    const float* __restrict__ Wfc1, const float* __restrict__ bfc1,
    const float* __restrict__ Wout, const float* __restrict__ bout,
    float* __restrict__ out)                 // [B]
{
  __shared__ __align__(16) __bf16 sWa[48 * 64 * 8];  // 48 KB, frag f = t*8+s
  __shared__ __align__(16) __bf16 sW1[9 * 64 * 8];   //  9 KB, frag f = t*3+s
  __shared__ __align__(16) __bf16 sHS[4][16 * C1];   // 12 KB: hist-scores(+ba), row=it
  __shared__ float sRed[4][128];                     //  2 KB
  __shared__ float sAgg2[128];
  __shared__ float sComb[2 * H];
  __shared__ float sP[4];

  const int tid  = threadIdx.x;
  const int wave = tid >> 6;     // 0..3
  const int lane = tid & 63;
  const int g    = lane >> 4;
  const int c    = lane & 15;

  // ---- Stage Wa/W1 as pre-arranged lane fragments (16B/lane contiguous) ----
  for (int e = tid; e < 48 * 64; e += 256) {
    int lv = e & 63, frag = e >> 6;
    int s = frag & 7, t = frag >> 3;
    int k0 = s * 32 + ((lv >> 4) << 3);
    int cc = t * 16 + (lv & 15);
    bf16x8 v;
    #pragma unroll
    for (int j = 0; j < 8; ++j) v[j] = (__bf16)Wa[(k0 + j) * C1 + cc];
    *(bf16x8*)&sWa[e * 8] = v;
  }
  for (int e = tid; e < 9 * 64; e += 256) {
    int lv = e & 63, frag = e >> 6;
    int s = frag % 3, t = frag / 3;
    int k0 = s * 32 + ((lv >> 4) << 3);
    int cc = t * 16 + (lv & 15);
    bf16x8 v;
    #pragma unroll
    for (int j = 0; j < 8; ++j) v[j] = (__bf16)W1[(k0 + j) * C2 + cc];
    *(bf16x8*)&sW1[e * 8] = v;
  }

  // Per-lane constants (g-indexed: rows of the transposed outputs)
  const f32x4 b1v0 = *(const f32x4*)&b1[ 0 + 4 * g];
  const f32x4 b1v1 = *(const f32x4*)&b1[16 + 4 * g];
  const f32x4 b1v2 = *(const f32x4*)&b1[32 + 4 * g];
  const f32x4 b2v  = *(const f32x4*)&b2[4 * g];
  const f32x4 w3v  = *(const f32x4*)&W3[4 * g];
  bf16x8 w2f[2];   // W2^T A-frags: W2[32s+8g+j][c], zeros for k>=48
  #pragma unroll
  for (int s = 0; s < 2; ++s)
    #pragma unroll
    for (int j = 0; j < 8; ++j) {
      int k = s * 32 + g * 8 + j;
      w2f[s][j] = (k < C2) ? (__bf16)W2[k * C3 + c] : (__bf16)0.f;
    }

  __syncthreads();

  const int bb = blockIdx.x;            // one b per block
  const int wl = wave;                  // wave's l-offset (stride 4)
  __bf16* HS = sHS[wave];
  const int nIter = (L - wl + 3) / 4;   // 13,13,12,12

  // ---- Prologue (unswapped, verified): batched hist GEMM over the wave's
  //      l's; rows = it, cols = j. HS[it][j] = hist@Wa_top + ba. ----
  {
    float ba_r[6];
    #pragma unroll
    for (int t = 0; t < 6; ++t) ba_r[t] = ba[t * 16 + c];
    int li  = wl + 4 * c;
    int idx = (li < L) ? history[bb * L + li] : history[bb * L];
    const float* hr = item_table + (size_t)idx * H;
    f32x4 acch[6];
    #pragma unroll
    for (int t = 0; t < 6; ++t) acch[t] = (f32x4){0.f, 0.f, 0.f, 0.f};
    #pragma unroll
    for (int s = 0; s < 4; ++s) {
      const float* p = hr + s * 32 + g * 8;
      bf16x8 a = cvt8(*(const float4*)p, *(const float4*)(p + 4));
      #pragma unroll
      for (int t = 0; t < 6; ++t)
        acch[t] = __builtin_amdgcn_mfma_f32_16x16x32_bf16(
            a, *(const bf16x8*)&sWa[((t * 8 + s) * 64 + lane) * 8], acch[t], 0, 0, 0);
    }
    #pragma unroll
    for (int t = 0; t < 6; ++t)
      #pragma unroll
      for (int r = 0; r < 4; ++r)
        HS[(4 * g + r) * C1 + t * 16 + c] = (__bf16)(acch[t][r] + ba_r[t]);
  }

  // ---- Main loop: swapped MLP, zero LDS writes, 1-deep prefetch ----
  const float* nb0 = neighbor_emb + (size_t)(bb * L + wl) * (N * H) + c * H + g * 8;
  const size_t TS = (size_t)4 * N * H;
  float4 nf[8];
  #pragma unroll
  for (int s = 0; s < 4; ++s) {
    nf[2 * s]     = *(const float4*)(nb0 + s * 32);
    nf[2 * s + 1] = *(const float4*)(nb0 + s * 32 + 4);
  }
  float aggp[32];
  #pragma unroll
  for (int i = 0; i < 32; ++i) aggp[i] = 0.f;

  const int  src_lo = ((g & 1) << 5) | c;   // lane 2(g&1)*16 + c
  const int  src_hi = src_lo + 16;
  const bool gh     = (g >> 1) & 1;

  for (int it = 0; it < nIter; ++it) {
    // B-frags for L1 straight from prefetch regs; then prefetch it+1.
    bf16x8 aA[4];
    #pragma unroll
    for (int s = 0; s < 4; ++s) aA[s] = cvt8(nf[2 * s], nf[2 * s + 1]);
    if (it + 1 < nIter) {
      const float* p = nb0 + (size_t)(it + 1) * TS;
      #pragma unroll
      for (int s = 0; s < 4; ++s) {
        nf[2 * s]     = *(const float4*)(p + s * 32);
        nf[2 * s + 1] = *(const float4*)(p + s * 32 + 4);
      }
    }

    // ---- L1 swapped: acc[t] = S^T rows 16t+4g+r, col n=c.
    //      C-init = HS[it][16t+4g+r] (hist part + ba), broadcast b64 reads.
    f32x4 acc[6];
    #pragma unroll
    for (int t = 0; t < 6; ++t) {
      uint2 hw = *(const uint2*)&HS[it * C1 + 16 * t + 4 * g];
      acc[t][0] = bf16lo(hw.x); acc[t][1] = bf16hi(hw.x);
      acc[t][2] = bf16lo(hw.y); acc[t][3] = bf16hi(hw.y);
    }
    #pragma unroll
    for (int s = 0; s < 4; ++s)
      #pragma unroll
      for (int t = 0; t < 6; ++t)
        acc[t] = __builtin_amdgcn_mfma_f32_16x16x32_bf16(
            *(const bf16x8*)&sWa[((t * 8 + 4 + s) * 64 + lane) * 8], aA[s],
            acc[t], 0, 0, 0);
    // relu + pack to bf16 pairs: pku[t][q] = (j=16t+4g+2q, +1)
    unsigned pku[6][2];
    #pragma unroll
    for (int t = 0; t < 6; ++t) {
      pku[t][0] = pkbf(fmaxf(acc[t][0], 0.f), fmaxf(acc[t][1], 0.f));
      pku[t][1] = pkbf(fmaxf(acc[t][2], 0.f), fmaxf(acc[t][3], 0.f));
    }

    // ---- L2 swapped: B-frags via two-round shuffle, C-init = b1 ----
    f32x4 acc2[3] = {b1v0, b1v1, b1v2};
    #pragma unroll
    for (int s = 0; s < 3; ++s) {
      unsigned a0 = __shfl((int)pku[2 * s][0], src_lo);
      unsigned a1 = __shfl((int)pku[2 * s][1], src_lo);
      unsigned a2 = __shfl((int)pku[2 * s][0], src_hi);
      unsigned a3 = __shfl((int)pku[2 * s][1], src_hi);
      unsigned d0 = __shfl((int)pku[2 * s + 1][0], src_lo);
      unsigned d1 = __shfl((int)pku[2 * s + 1][1], src_lo);
      unsigned d2 = __shfl((int)pku[2 * s + 1][0], src_hi);
      unsigned d3 = __shfl((int)pku[2 * s + 1][1], src_hi);
      u32x4 wv = {gh ? d0 : a0, gh ? d1 : a1, gh ? d2 : a2, gh ? d3 : a3};
      bf16x8 bf2 = __builtin_bit_cast(bf16x8, wv);
      #pragma unroll
      for (int t2 = 0; t2 < 3; ++t2)
        acc2[t2] = __builtin_amdgcn_mfma_f32_16x16x32_bf16(
            *(const bf16x8*)&sW1[((t2 * 3 + s) * 64 + lane) * 8], bf2,
            acc2[t2], 0, 0, 0);
    }
    unsigned pk2[3][2];
    #pragma unroll
    for (int t2 = 0; t2 < 3; ++t2) {
      pk2[t2][0] = pkbf(fmaxf(acc2[t2][0], 0.f), fmaxf(acc2[t2][1], 0.f));
      pk2[t2][1] = pkbf(fmaxf(acc2[t2][2], 0.f), fmaxf(acc2[t2][3], 0.f));
    }

    // ---- L3 swapped: K=64 (k>=48 zero), C-init = b2 ----
    f32x4 acc3 = b2v;
    {
      unsigned a0 = __shfl((int)pk2[0][0], src_lo);
      unsigned a1 = __shfl((int)pk2[0][1], src_lo);
      unsigned a2 = __shfl((int)pk2[0][0], src_hi);
      unsigned a3 = __shfl((int)pk2[0][1], src_hi);
      unsigned d0 = __shfl((int)pk2[1][0], src_lo);
      unsigned d1 = __shfl((int)pk2[1][1], src_lo);
      unsigned d2 = __shfl((int)pk2[1][0], src_hi);
      unsigned d3 = __shfl((int)pk2[1][1], src_hi);
      u32x4 wv = {gh ? d0 : a0, gh ? d1 : a1, gh ? d2 : a2, gh ? d3 : a3};
      acc3 = __builtin_amdgcn_mfma_f32_16x16x32_bf16(
          w2f[0], __builtin_bit_cast(bf16x8, wv), acc3, 0, 0, 0);
      unsigned e0 = __shfl((int)pk2[2][0], src_lo);
      unsigned e1 = __shfl((int)pk2[2][1], src_lo);
      unsigned e2 = __shfl((int)pk2[2][0], src_hi);
      unsigned e3 = __shfl((int)pk2[2][1], src_hi);
      u32x4 wv2 = {gh ? 0u : e0, gh ? 0u : e1, gh ? 0u : e2, gh ? 0u : e3};
      acc3 = __builtin_amdgcn_mfma_f32_16x16x32_bf16(
          w2f[1], __builtin_bit_cast(bf16x8, wv2), acc3, 0, 0, 0);
    }

    // ---- Logit: lane holds h2^T rows p=4g+r for n=c; reduce over g.
    //      Softmax without max-subtract: logits O(0.2) by scale analysis
    //      (validated r7/r8/r11: absmax 0.0). ----
    float lg = 0.f;
    #pragma unroll
    for (int r = 0; r < 4; ++r) lg = fmaf(fmaxf(acc3[r], 0.f), w3v[r], lg);
    lg += __shfl_xor(lg, 16);
    lg += __shfl_xor(lg, 32);
    float e = __expf(lg);
    float se = e;
    se += __shfl_xor(se, 1);
    se += __shfl_xor(se, 2);
    se += __shfl_xor(se, 4);
    se += __shfl_xor(se, 8);
    const float w = e / se;

    // ---- In-register aggregate: lane weights its own 32 values (n=c) ----
    #pragma unroll
    for (int s = 0; s < 4; ++s) {
      u32x4 au = __builtin_bit_cast(u32x4, aA[s]);
      #pragma unroll
      for (int q = 0; q < 4; ++q) {
        unsigned u = au[q];
        aggp[s * 8 + 2 * q]     = fmaf(w, bf16lo(u), aggp[s * 8 + 2 * q]);
        aggp[s * 8 + 2 * q + 1] = fmaf(w, bf16hi(u), aggp[s * 8 + 2 * q + 1]);
      }
    }
  }

  // ---- Reduce aggp over c (16 lanes) ----
  #pragma unroll
  for (int off = 1; off < 16; off <<= 1)
    #pragma unroll
    for (int i = 0; i < 32; ++i) aggp[i] += __shfl_xor(aggp[i], off);
  if (c == 0) {
    #pragma unroll
    for (int s = 0; s < 4; ++s) {
      float4 v0 = {aggp[8 * s + 0], aggp[8 * s + 1], aggp[8 * s + 2], aggp[8 * s + 3]};
      float4 v1 = {aggp[8 * s + 4], aggp[8 * s + 5], aggp[8 * s + 6], aggp[8 * s + 7]};
      *(float4*)&sRed[wave][32 * s + 8 * g]     = v0;
      *(float4*)&sRed[wave][32 * s + 8 * g + 4] = v1;
    }
  }
  __syncthreads();

  // ---- Fused head (one b): mean -> @Wmh -> [user|pooled] -> fc1 -> sigmoid ----
  if (tid < 128) {
    float s = 0.f;
    #pragma unroll
    for (int w = 0; w < 4; ++w) s += sRed[w][tid];
    sAgg2[tid] = s * (1.0f / L);
    sComb[tid] = user_table[(size_t)user_ids[bb] * H + tid];
  }
  __syncthreads();
  if (tid < 128) {
    float p = bmh[tid];
    #pragma unroll 8
    for (int k = 0; k < H; ++k) p = fmaf(sAgg2[k], Wmh[k * H + tid], p);
    sComb[H + tid] = p;
  }
  __syncthreads();
  if (tid < 128) {
    float hd = bfc1[tid];
    #pragma unroll 8
    for (int k = 0; k < 2 * H; ++k) hd = fmaf(sComb[k], Wfc1[k * H + tid], hd);
    hd = fmaxf(hd, 0.f);
    float partial = hd * Wout[tid];
    #pragma unroll
    for (int off = 32; off > 0; off >>= 1) partial += __shfl_down(partial, off);
    if (lane == 0) sP[wave] = partial;
  }
  __syncthreads();
  if (tid == 0)
    out[bb] = 1.f / (1.f + __expf(-(sP[0] + sP[1] + bout[0])));
}

extern "C" void kernel_launch(void* const* d_in, const int* in_sizes, int n_in,
                              void* d_out, int out_size, void* d_ws, size_t ws_size,
                              hipStream_t stream) {
  const int*   user_ids     = (const int*)  d_in[0];
  // d_in[1] = item_ids — unused (item_emb computed but unused in reference)
  const int*   history      = (const int*)  d_in[2];
  const float* neighbor_emb = (const float*)d_in[3];
  const float* user_table   = (const float*)d_in[4];
  const float* item_table   = (const float*)d_in[5];
  const float* Wa   = (const float*)d_in[6];
  const float* ba   = (const float*)d_in[7];
  const float* W1   = (const float*)d_in[8];
  const float* b1   = (const float*)d_in[9];
  const float* W2   = (const float*)d_in[10];
  const float* b2   = (const float*)d_in[11];
  const float* W3   = (const float*)d_in[12];
  // d_in[13] = b3 — constant shift over the softmax axis, cancels exactly
  const float* Wmh  = (const float*)d_in[14];
  const float* bmh  = (const float*)d_in[15];
  const float* Wfc1 = (const float*)d_in[16];
  const float* bfc1 = (const float*)d_in[17];
  const float* Wout = (const float*)d_in[18];
  const float* bout = (const float*)d_in[19];

  float* out = (float*)d_out;   // [B]

  hipLaunchKernelGGL(fused_kernel, dim3(B), dim3(256), 0, stream,
                     user_ids, history, neighbor_emb, user_table, item_table,
                     Wa, ba, W1, b1, W2, b2, W3,
                     Wmh, bmh, Wfc1, bfc1, Wout, bout, out);
}

// Round 16
// 59.119 us; speedup vs baseline: 1.5497x; 1.5497x over previous
//
#include <hip/hip_runtime.h>

// Problem constants
constexpr int B  = 512, L = 50, N = 16, H = 128;
constexpr int C1 = 96, C2 = 48, C3 = 16;

typedef __bf16   bf16x8 __attribute__((ext_vector_type(8)));
typedef float    f32x4  __attribute__((ext_vector_type(4)));
typedef unsigned u32x4  __attribute__((ext_vector_type(4)));

__device__ __forceinline__ bf16x8 cvt8(float4 a, float4 b) {
  bf16x8 r;
  r[0] = (__bf16)a.x; r[1] = (__bf16)a.y; r[2] = (__bf16)a.z; r[3] = (__bf16)a.w;
  r[4] = (__bf16)b.x; r[5] = (__bf16)b.y; r[6] = (__bf16)b.z; r[7] = (__bf16)b.w;
  return r;
}
__device__ __forceinline__ float bf16lo(unsigned u) { return __uint_as_float(u << 16); }
__device__ __forceinline__ float bf16hi(unsigned u) { return __uint_as_float(u & 0xffff0000u); }
// pack two f32 -> one u32 of 2 bf16 (RNE), single instruction
__device__ __forceinline__ unsigned pkbf(float lo, float hi) {
  unsigned r;
  asm("v_cvt_pk_bf16_f32 %0, %1, %2" : "=v"(r) : "v"(lo), "v"(hi));
  return r;
}

// MFMA 16x16x32 bf16 lane mapping (verified m89/m91):
//   A: row = lane&15, k = 32*step + 8*(lane>>4) + j   (B identical, col=lane&15)
//   D: col = lane&15, row = 4*(lane>>4) + reg
//
// Register-file physics (r12/r15 measured): true arch demand = 164; unified
// file gives 2 waves/SIMD only if arch+acc <= 256. r12 {cap 128, 2 waves,
// 8 MB spill} = 63 us beats r15 {164 regs, 1 wave, 0 spill} = 92 us.
// r16: cut ~28 persistent regs (b1/b2/W3/W2-frag constants) by homing them
// in LDS and re-reading per iteration. LICM would hoist them back -> each
// read is indexed by a laundered per-iter offset (asm "+v"), forcing a
// genuine per-iter ds_read_b128 broadcast (7/iter, ~60cyc, off-chain).
__global__ __launch_bounds__(256, 2) void fused_kernel(
    const int*   __restrict__ user_ids,      // [B]
    const int*   __restrict__ history,       // [B][L]
    const float* __restrict__ neighbor_emb,  // [B][L][N][H]
    const float* __restrict__ user_table,    // [100000][H]
    const float* __restrict__ item_table,    // [100000][H]
    const float* __restrict__ Wa,  const float* __restrict__ ba,
    const float* __restrict__ W1,  const float* __restrict__ b1,
    const float* __restrict__ W2,  const float* __restrict__ b2,
    const float* __restrict__ W3,
    const float* __restrict__ Wmh,  const float* __restrict__ bmh,
    const float* __restrict__ Wfc1, const float* __restrict__ bfc1,
    const float* __restrict__ Wout, const float* __restrict__ bout,
    float* __restrict__ out)                 // [B]
{
  __shared__ __align__(16) __bf16 sWa[48 * 64 * 8];  // 48 KB, frag f = t*8+s
  __shared__ __align__(16) __bf16 sW1[9 * 64 * 8];   //  9 KB, frag f = t*3+s
  __shared__ __align__(16) __bf16 sW2f[2 * 64 * 8];  //  2 KB: W2^T frags (K-pad 64)
  __shared__ __align__(16) __bf16 sHS[4][16 * C1];   // 12 KB: hist-scores(+ba), row=it
  __shared__ __align__(16) float sB1[48];            // biases homed in LDS
  __shared__ __align__(16) float sB2[16];
  __shared__ __align__(16) float sW3v[16];
  __shared__ float sRed[4][128];                     //  2 KB
  __shared__ float sAgg2[128];
  __shared__ float sComb[2 * H];
  __shared__ float sP[4];

  const int tid  = threadIdx.x;
  const int wave = tid >> 6;     // 0..3
  const int lane = tid & 63;
  const int g    = lane >> 4;
  const int c    = lane & 15;

  // ---- Stage Wa/W1/W2 as pre-arranged lane fragments (16B/lane) ----
  for (int e = tid; e < 48 * 64; e += 256) {
    int lv = e & 63, frag = e >> 6;
    int s = frag & 7, t = frag >> 3;
    int k0 = s * 32 + ((lv >> 4) << 3);
    int cc = t * 16 + (lv & 15);
    bf16x8 v;
    #pragma unroll
    for (int j = 0; j < 8; ++j) v[j] = (__bf16)Wa[(k0 + j) * C1 + cc];
    *(bf16x8*)&sWa[e * 8] = v;
  }
  for (int e = tid; e < 9 * 64; e += 256) {
    int lv = e & 63, frag = e >> 6;
    int s = frag % 3, t = frag / 3;
    int k0 = s * 32 + ((lv >> 4) << 3);
    int cc = t * 16 + (lv & 15);
    bf16x8 v;
    #pragma unroll
    for (int j = 0; j < 8; ++j) v[j] = (__bf16)W1[(k0 + j) * C2 + cc];
    *(bf16x8*)&sW1[e * 8] = v;
  }
  for (int e = tid; e < 2 * 64; e += 256) {
    int lv = e & 63, s = e >> 6;
    bf16x8 v;
    #pragma unroll
    for (int j = 0; j < 8; ++j) {
      int k = s * 32 + ((lv >> 4) << 3) + j;
      v[j] = (k < C2) ? (__bf16)W2[k * C3 + (lv & 15)] : (__bf16)0.f;
    }
    *(bf16x8*)&sW2f[e * 8] = v;
  }
  if (tid < 48) sB1[tid] = b1[tid];
  if (tid < 16) { sB2[tid] = b2[tid]; sW3v[tid] = W3[tid]; }

  __syncthreads();

  const int bb = blockIdx.x;            // one b per block
  const int wl = wave;                  // wave's l-offset (stride 4)
  __bf16* HS = sHS[wave];
  const int nIter = (L - wl + 3) / 4;   // 13,13,12,12

  // ---- Prologue (unswapped, verified): batched hist GEMM over the wave's
  //      l's; rows = it, cols = j. HS[it][j] = hist@Wa_top + ba. ----
  {
    float ba_r[6];
    #pragma unroll
    for (int t = 0; t < 6; ++t) ba_r[t] = ba[t * 16 + c];
    int li  = wl + 4 * c;
    int idx = (li < L) ? history[bb * L + li] : history[bb * L];
    const float* hr = item_table + (size_t)idx * H;
    f32x4 acch[6];
    #pragma unroll
    for (int t = 0; t < 6; ++t) acch[t] = (f32x4){0.f, 0.f, 0.f, 0.f};
    #pragma unroll
    for (int s = 0; s < 4; ++s) {
      const float* p = hr + s * 32 + g * 8;
      bf16x8 a = cvt8(*(const float4*)p, *(const float4*)(p + 4));
      #pragma unroll
      for (int t = 0; t < 6; ++t)
        acch[t] = __builtin_amdgcn_mfma_f32_16x16x32_bf16(
            a, *(const bf16x8*)&sWa[((t * 8 + s) * 64 + lane) * 8], acch[t], 0, 0, 0);
    }
    #pragma unroll
    for (int t = 0; t < 6; ++t)
      #pragma unroll
      for (int r = 0; r < 4; ++r)
        HS[(4 * g + r) * C1 + t * 16 + c] = (__bf16)(acch[t][r] + ba_r[t]);
  }

  // ---- Main loop: swapped MLP, zero in-loop LDS writes, 1-deep prefetch ----
  const float* nb0 = neighbor_emb + (size_t)(bb * L + wl) * (N * H) + c * H + g * 8;
  const size_t TS = (size_t)4 * N * H;
  float4 nf[8];
  #pragma unroll
  for (int s = 0; s < 4; ++s) {
    nf[2 * s]     = *(const float4*)(nb0 + s * 32);
    nf[2 * s + 1] = *(const float4*)(nb0 + s * 32 + 4);
  }
  float aggp[32];
  #pragma unroll
  for (int i = 0; i < 32; ++i) aggp[i] = 0.f;

  const int  src_lo = ((g & 1) << 5) | c;   // lane 2(g&1)*16 + c
  const int  src_hi = src_lo + 16;
  const bool gh     = (g >> 1) & 1;

  for (int it = 0; it < nIter; ++it) {
    // B-frags for L1 straight from prefetch regs; then prefetch it+1.
    bf16x8 aA[4];
    #pragma unroll
    for (int s = 0; s < 4; ++s) aA[s] = cvt8(nf[2 * s], nf[2 * s + 1]);
    if (it + 1 < nIter) {
      const float* p = nb0 + (size_t)(it + 1) * TS;
      #pragma unroll
      for (int s = 0; s < 4; ++s) {
        nf[2 * s]     = *(const float4*)(p + s * 32);
        nf[2 * s + 1] = *(const float4*)(p + s * 32 + 4);
      }
    }

    // Laundered per-iter offset: forces the LDS-homed constants below to be
    // RE-READ each iteration (defeats LICM re-hoisting them into registers).
    unsigned lo_ = 0;
    asm volatile("" : "+v"(lo_));
    // Per-iter constant reads (broadcast ds_read_b128, off the critical chain)
    const f32x4 b1v0 = *(const f32x4*)&sB1[ 0 + 4 * g + lo_];
    const f32x4 b1v1 = *(const f32x4*)&sB1[16 + 4 * g + lo_];
    const f32x4 b1v2 = *(const f32x4*)&sB1[32 + 4 * g + lo_];
    const f32x4 b2v  = *(const f32x4*)&sB2[4 * g + lo_];
    const f32x4 w3v  = *(const f32x4*)&sW3v[4 * g + lo_];
    const bf16x8 w2f0 = *(const bf16x8*)&sW2f[(0 * 64 + lane) * 8 + lo_ * 8];
    const bf16x8 w2f1 = *(const bf16x8*)&sW2f[(1 * 64 + lane) * 8 + lo_ * 8];

    // ---- L1 swapped: acc[t] = S^T rows 16t+4g+r, col n=c.
    //      C-init = HS[it][16t+4g+r] (hist part + ba), broadcast b64 reads.
    f32x4 acc[6];
    #pragma unroll
    for (int t = 0; t < 6; ++t) {
      uint2 hw = *(const uint2*)&HS[it * C1 + 16 * t + 4 * g];
      acc[t][0] = bf16lo(hw.x); acc[t][1] = bf16hi(hw.x);
      acc[t][2] = bf16lo(hw.y); acc[t][3] = bf16hi(hw.y);
    }
    #pragma unroll
    for (int s = 0; s < 4; ++s)
      #pragma unroll
      for (int t = 0; t < 6; ++t)
        acc[t] = __builtin_amdgcn_mfma_f32_16x16x32_bf16(
            *(const bf16x8*)&sWa[((t * 8 + 4 + s) * 64 + lane) * 8], aA[s],
            acc[t], 0, 0, 0);
    // relu + pack to bf16 pairs: pku[t][q] = (j=16t+4g+2q, +1)
    unsigned pku[6][2];
    #pragma unroll
    for (int t = 0; t < 6; ++t) {
      pku[t][0] = pkbf(fmaxf(acc[t][0], 0.f), fmaxf(acc[t][1], 0.f));
      pku[t][1] = pkbf(fmaxf(acc[t][2], 0.f), fmaxf(acc[t][3], 0.f));
    }

    // ---- L2 swapped: B-frags via two-round shuffle, C-init = b1 ----
    f32x4 acc2[3] = {b1v0, b1v1, b1v2};
    #pragma unroll
    for (int s = 0; s < 3; ++s) {
      unsigned a0 = __shfl((int)pku[2 * s][0], src_lo);
      unsigned a1 = __shfl((int)pku[2 * s][1], src_lo);
      unsigned a2 = __shfl((int)pku[2 * s][0], src_hi);
      unsigned a3 = __shfl((int)pku[2 * s][1], src_hi);
      unsigned d0 = __shfl((int)pku[2 * s + 1][0], src_lo);
      unsigned d1 = __shfl((int)pku[2 * s + 1][1], src_lo);
      unsigned d2 = __shfl((int)pku[2 * s + 1][0], src_hi);
      unsigned d3 = __shfl((int)pku[2 * s + 1][1], src_hi);
      u32x4 wv = {gh ? d0 : a0, gh ? d1 : a1, gh ? d2 : a2, gh ? d3 : a3};
      bf16x8 bf2 = __builtin_bit_cast(bf16x8, wv);
      #pragma unroll
      for (int t2 = 0; t2 < 3; ++t2)
        acc2[t2] = __builtin_amdgcn_mfma_f32_16x16x32_bf16(
            *(const bf16x8*)&sW1[((t2 * 3 + s) * 64 + lane) * 8], bf2,
            acc2[t2], 0, 0, 0);
    }
    unsigned pk2[3][2];
    #pragma unroll
    for (int t2 = 0; t2 < 3; ++t2) {
      pk2[t2][0] = pkbf(fmaxf(acc2[t2][0], 0.f), fmaxf(acc2[t2][1], 0.f));
      pk2[t2][1] = pkbf(fmaxf(acc2[t2][2], 0.f), fmaxf(acc2[t2][3], 0.f));
    }

    // ---- L3 swapped: K=64 (k>=48 zero), C-init = b2 ----
    f32x4 acc3 = b2v;
    {
      unsigned a0 = __shfl((int)pk2[0][0], src_lo);
      unsigned a1 = __shfl((int)pk2[0][1], src_lo);
      unsigned a2 = __shfl((int)pk2[0][0], src_hi);
      unsigned a3 = __shfl((int)pk2[0][1], src_hi);
      unsigned d0 = __shfl((int)pk2[1][0], src_lo);
      unsigned d1 = __shfl((int)pk2[1][1], src_lo);
      unsigned d2 = __shfl((int)pk2[1][0], src_hi);
      unsigned d3 = __shfl((int)pk2[1][1], src_hi);
      u32x4 wv = {gh ? d0 : a0, gh ? d1 : a1, gh ? d2 : a2, gh ? d3 : a3};
      acc3 = __builtin_amdgcn_mfma_f32_16x16x32_bf16(
          w2f0, __builtin_bit_cast(bf16x8, wv), acc3, 0, 0, 0);
      unsigned e0 = __shfl((int)pk2[2][0], src_lo);
      unsigned e1 = __shfl((int)pk2[2][1], src_lo);
      unsigned e2 = __shfl((int)pk2[2][0], src_hi);
      unsigned e3 = __shfl((int)pk2[2][1], src_hi);
      u32x4 wv2 = {gh ? 0u : e0, gh ? 0u : e1, gh ? 0u : e2, gh ? 0u : e3};
      acc3 = __builtin_amdgcn_mfma_f32_16x16x32_bf16(
          w2f1, __builtin_bit_cast(bf16x8, wv2), acc3, 0, 0, 0);
    }

    // ---- Logit: lane holds h2^T rows p=4g+r for n=c; reduce over g.
    //      Softmax without max-subtract: logits O(0.2) by scale analysis
    //      (validated r7/r8/r11: absmax 0.0). ----
    float lg = 0.f;
    #pragma unroll
    for (int r = 0; r < 4; ++r) lg = fmaf(fmaxf(acc3[r], 0.f), w3v[r], lg);
    lg += __shfl_xor(lg, 16);
    lg += __shfl_xor(lg, 32);
    float e = __expf(lg);
    float se = e;
    se += __shfl_xor(se, 1);
    se += __shfl_xor(se, 2);
    se += __shfl_xor(se, 4);
    se += __shfl_xor(se, 8);
    const float w = e / se;

    // ---- In-register aggregate: lane weights its own 32 values (n=c) ----
    #pragma unroll
    for (int s = 0; s < 4; ++s) {
      u32x4 au = __builtin_bit_cast(u32x4, aA[s]);
      #pragma unroll
      for (int q = 0; q < 4; ++q) {
        unsigned u = au[q];
        aggp[s * 8 + 2 * q]     = fmaf(w, bf16lo(u), aggp[s * 8 + 2 * q]);
        aggp[s * 8 + 2 * q + 1] = fmaf(w, bf16hi(u), aggp[s * 8 + 2 * q + 1]);
      }
    }
  }

  // ---- Reduce aggp over c (16 lanes) ----
  #pragma unroll
  for (int off = 1; off < 16; off <<= 1)
    #pragma unroll
    for (int i = 0; i < 32; ++i) aggp[i] += __shfl_xor(aggp[i], off);
  if (c == 0) {
    #pragma unroll
    for (int s = 0; s < 4; ++s) {
      float4 v0 = {aggp[8 * s + 0], aggp[8 * s + 1], aggp[8 * s + 2], aggp[8 * s + 3]};
      float4 v1 = {aggp[8 * s + 4], aggp[8 * s + 5], aggp[8 * s + 6], aggp[8 * s + 7]};
      *(float4*)&sRed[wave][32 * s + 8 * g]     = v0;
      *(float4*)&sRed[wave][32 * s + 8 * g + 4] = v1;
    }
  }
  __syncthreads();

  // ---- Fused head (one b): mean -> @Wmh -> [user|pooled] -> fc1 -> sigmoid ----
  if (tid < 128) {
    float s = 0.f;
    #pragma unroll
    for (int w = 0; w < 4; ++w) s += sRed[w][tid];
    sAgg2[tid] = s * (1.0f / L);
    sComb[tid] = user_table[(size_t)user_ids[bb] * H + tid];
  }
  __syncthreads();
  if (tid < 128) {
    float p = bmh[tid];
    #pragma unroll 8
    for (int k = 0; k < H; ++k) p = fmaf(sAgg2[k], Wmh[k * H + tid], p);
    sComb[H + tid] = p;
  }
  __syncthreads();
  if (tid < 128) {
    float hd = bfc1[tid];
    #pragma unroll 8
    for (int k = 0; k < 2 * H; ++k) hd = fmaf(sComb[k], Wfc1[k * H + tid], hd);
    hd = fmaxf(hd, 0.f);
    float partial = hd * Wout[tid];
    #pragma unroll
    for (int off = 32; off > 0; off >>= 1) partial += __shfl_down(partial, off);
    if (lane == 0) sP[wave] = partial;
  }
  __syncthreads();
  if (tid == 0)
    out[bb] = 1.f / (1.f + __expf(-(sP[0] + sP[1] + bout[0])));
}

extern "C" void kernel_launch(void* const* d_in, const int* in_sizes, int n_in,
                              void* d_out, int out_size, void* d_ws, size_t ws_size,
                              hipStream_t stream) {
  const int*   user_ids     = (const int*)  d_in[0];
  // d_in[1] = item_ids — unused (item_emb computed but unused in reference)
  const int*   history      = (const int*)  d_in[2];
  const float* neighbor_emb = (const float*)d_in[3];
  const float* user_table   = (const float*)d_in[4];
  const float* item_table   = (const float*)d_in[5];
  const float* Wa   = (const float*)d_in[6];
  const float* ba   = (const float*)d_in[7];
  const float* W1   = (const float*)d_in[8];
  const float* b1   = (const float*)d_in[9];
  const float* W2   = (const float*)d_in[10];
  const float* b2   = (const float*)d_in[11];
  const float* W3   = (const float*)d_in[12];
  // d_in[13] = b3 — constant shift over the softmax axis, cancels exactly
  const float* Wmh  = (const float*)d_in[14];
  const float* bmh  = (const float*)d_in[15];
  const float* Wfc1 = (const float*)d_in[16];
  const float* bfc1 = (const float*)d_in[17];
  const float* Wout = (const float*)d_in[18];
  const float* bout = (const float*)d_in[19];

  float* out = (float*)d_out;   // [B]

  hipLaunchKernelGGL(fused_kernel, dim3(B), dim3(256), 0, stream,
                     user_ids, history, neighbor_emb, user_table, item_table,
                     Wa, ba, W1, b1, W2, b2, W3,
                     Wmh, bmh, Wfc1, bfc1, Wout, bout, out);
}